// Round 7
// baseline (308.356 us; speedup 1.0000x reference)
//
#include <hip/hip_runtime.h>
#include <math.h>

#define N_NODES   100000
#define N_EDGES   1600000
#define D         64
#define NEG_SLOPE 0.2f

#define SCAN_CHUNK 1024
#define NB_SCAN    ((N_NODES + SCAN_CHUNK - 1) / SCAN_CHUNK)   // 98

#define AGG_CHUNK 128   // edges per online-softmax chunk (LDS buffered)

typedef __attribute__((ext_vector_type(8))) _Float16 half8;
typedef __attribute__((ext_vector_type(2))) _Float16 half2v;
typedef __attribute__((ext_vector_type(4))) float floatx4;

// fp32 -> bf16 bits, round-to-nearest-even
__device__ __forceinline__ unsigned short bfbits(float x) {
    unsigned u = __float_as_uint(x);
    u += 0x7fffu + ((u >> 16) & 1u);
    return (unsigned short)(u >> 16);
}
__device__ __forceinline__ float blo(unsigned v) { return __uint_as_float(v << 16); }
__device__ __forceinline__ float bhi(unsigned v) { return __uint_as_float(v & 0xffff0000u); }
// fp32 -> fp16 bits (RTE)
__device__ __forceinline__ unsigned short h16(float x) {
    union { _Float16 h; unsigned short u; } c; c.h = (_Float16)x; return c.u;
}
__device__ __forceinline__ half2v u2h(unsigned v) {
    union { unsigned u; half2v h; } c; c.u = v; return c.h;
}
__device__ __forceinline__ float fdot2(unsigned a, half2v b, float c) {
#if __has_builtin(__builtin_amdgcn_fdot2)
    return __builtin_amdgcn_fdot2(u2h(a), b, c, false);
#else
    half2v ah = u2h(a);
    return c + (float)ah[0] * (float)b[0] + (float)ah[1] * (float)b[1];
#endif
}

// ---- K1: fp16-MFMA projection: q(fp32), k(fp16), f(bf16) = feat @ {Wq,Wk,Wf} + b
// Layouts (gfx950 16x16x32, dtype-independent C/D): A[m=lane&15][k=quad*8+j],
// B[n=lane&15][k=quad*8+j], D: col=lane&15, row=quad*4+reg. 100000 = 16*6250 (no tail).
#define WT_STRIDE 72            // fp16 elems; 144 B row stride (16B-aligned)
#define PROJ_BLOCKS 512
#define PROJ_WAVES  (PROJ_BLOCKS * 4)
__global__ __launch_bounds__(256, 2) void proj_k(
    const float* __restrict__ feat,
    const float* __restrict__ Wq, const float* __restrict__ bq,
    const float* __restrict__ Wk, const float* __restrict__ bk,
    const float* __restrict__ Wf, const float* __restrict__ bf,
    float* __restrict__ q, unsigned short* __restrict__ kh,
    unsigned short* __restrict__ fb) {

    __shared__ unsigned short wt[3 * 64 * WT_STRIDE];   // 27 KB, fp16 bits

    const int tid  = threadIdx.x;
    const int lane = tid & 63;
    const int wave = tid >> 6;
    const int m    = lane & 15;
    const int quad = lane >> 4;

    // stage W^T into LDS as fp16: wt[w][n][k]
    for (int idx = tid; idx < 64 * 64; idx += 256) {
        int i = idx >> 6, d = idx & 63;                  // i = k-dim, d = out-dim
        int o = d * WT_STRIDE + i;
        wt[0 * 64 * WT_STRIDE + o] = h16(Wq[idx]);
        wt[1 * 64 * WT_STRIDE + o] = h16(Wk[idx]);
        wt[2 * 64 * WT_STRIDE + o] = h16(Wf[idx]);
    }
    __syncthreads();

    // register-resident B fragments + bias
    half8 Bf[3][4][2];
    float bias[3][4];
    #pragma unroll
    for (int w = 0; w < 3; w++)
        #pragma unroll
        for (int nt = 0; nt < 4; nt++) {
            int n = nt * 16 + m;
            #pragma unroll
            for (int ks = 0; ks < 2; ks++)
                Bf[w][nt][ks] = *(const half8*)&wt[(w * 64 + n) * WT_STRIDE + ks * 32 + quad * 8];
        }
    #pragma unroll
    for (int nt = 0; nt < 4; nt++) {
        int n = nt * 16 + m;
        bias[0][nt] = bq[n]; bias[1][nt] = bk[n]; bias[2][nt] = bf[n];
    }

    const int NT  = N_NODES / 16;          // 6250 exact
    const int wid = blockIdx.x * 4 + wave;

    for (int t = wid; t < NT; t += PROJ_WAVES) {
        int t0  = t * 16;
        int row = t0 + m;

        const floatx4* fr = (const floatx4*)(feat + (size_t)row * D + quad * 8);
        floatx4 x0 = fr[0], x1 = fr[1];    // k-dims quad*8..+7      (kstep 0)
        floatx4 x2 = fr[8], x3 = fr[9];    // k-dims 32+quad*8..+7   (kstep 1)

        half8 a0, a1;
        a0[0] = (_Float16)x0.x; a0[1] = (_Float16)x0.y;
        a0[2] = (_Float16)x0.z; a0[3] = (_Float16)x0.w;
        a0[4] = (_Float16)x1.x; a0[5] = (_Float16)x1.y;
        a0[6] = (_Float16)x1.z; a0[7] = (_Float16)x1.w;
        a1[0] = (_Float16)x2.x; a1[1] = (_Float16)x2.y;
        a1[2] = (_Float16)x2.z; a1[3] = (_Float16)x2.w;
        a1[4] = (_Float16)x3.x; a1[5] = (_Float16)x3.y;
        a1[6] = (_Float16)x3.z; a1[7] = (_Float16)x3.w;

        floatx4 acc[3][4];
        #pragma unroll
        for (int w = 0; w < 3; w++)
            #pragma unroll
            for (int nt = 0; nt < 4; nt++) {
                floatx4 c = {bias[w][nt], bias[w][nt], bias[w][nt], bias[w][nt]};
                c = __builtin_amdgcn_mfma_f32_16x16x32_f16(a0, Bf[w][nt][0], c, 0, 0, 0);
                c = __builtin_amdgcn_mfma_f32_16x16x32_f16(a1, Bf[w][nt][1], c, 0, 0, 0);
                acc[w][nt] = c;
            }

        #pragma unroll
        for (int nt = 0; nt < 4; nt++) {
            int dim = nt * 16 + m;
            #pragma unroll
            for (int r = 0; r < 4; r++) {
                int node = t0 + quad * 4 + r;
                size_t o = (size_t)node * D + dim;
                q[o]  = acc[0][nt][r];
                kh[o] = h16(acc[1][nt][r]);
                fb[o] = bfbits(acc[2][nt][r]);
            }
        }
    }
}

// ---- K2: histogram of dst, 4 edges/thread; slot written as int4 ----
__global__ __launch_bounds__(256) void hist_k(const int* __restrict__ dst,
                                              int* __restrict__ counts,
                                              int* __restrict__ slot) {
    int e0 = (blockIdx.x * 256 + threadIdx.x) * 4;
    if (e0 >= N_EDGES) return;               // N_EDGES % 4 == 0
    int4 d = *(const int4*)(dst + e0);
    int4 s;
    s.x = atomicAdd(&counts[d.x], 1);
    s.y = atomicAdd(&counts[d.y], 1);
    s.z = atomicAdd(&counts[d.z], 1);
    s.w = atomicAdd(&counts[d.w], 1);
    *(int4*)(slot + e0) = s;
}

// ---- K3a: per-block exclusive scan (1024 elems/block), raw blocksum out ----
__global__ __launch_bounds__(256) void scan1_k(const int* __restrict__ counts,
                                               int* __restrict__ rowstart,
                                               int* __restrict__ blocksum) {
    __shared__ int lds[256];
    int base = blockIdx.x * SCAN_CHUNK + threadIdx.x * 4;
    int c[4]; int s = 0;
    #pragma unroll
    for (int u = 0; u < 4; u++) {
        int idx = base + u;
        c[u] = (idx < N_NODES) ? counts[idx] : 0;
        s += c[u];
    }
    lds[threadIdx.x] = s;
    __syncthreads();
    for (int off = 1; off < 256; off <<= 1) {
        int v = (threadIdx.x >= off) ? lds[threadIdx.x - off] : 0;
        __syncthreads();
        lds[threadIdx.x] += v;
        __syncthreads();
    }
    int run = (threadIdx.x == 0) ? 0 : lds[threadIdx.x - 1];
    if (threadIdx.x == 255) blocksum[blockIdx.x] = lds[255];
    #pragma unroll
    for (int u = 0; u < 4; u++) {
        int idx = base + u;
        if (idx < N_NODES) rowstart[idx] = run;
        run += c[u];
    }
}

// ---- K3b: add block offsets (each block scans the raw blocksums itself) ----
__global__ __launch_bounds__(256) void scan23_k(int* __restrict__ rowstart,
                                                const int* __restrict__ blocksum) {
    __shared__ int lds[128];
    int t = threadIdx.x;
    if (t < 128) lds[t] = (t < NB_SCAN) ? blocksum[t] : 0;
    __syncthreads();
    for (int off = 1; off < 128; off <<= 1) {
        int v = 0;
        if (t < 128 && t >= off) v = lds[t - off];
        __syncthreads();
        if (t < 128) lds[t] += v;
        __syncthreads();
    }
    int i = blockIdx.x * 256 + t;
    if (i < N_NODES) {
        int ci = i / SCAN_CHUNK;
        rowstart[i] += (ci ? lds[ci - 1] : 0);
    }
    if (i == 0) rowstart[N_NODES] = N_EDGES;
}

// ---- K4: scatter (src<<7) byte-offsets into CSR slots, 4 edges/thread ----
__global__ __launch_bounds__(256) void scatter_k(
    const int* __restrict__ src, const int* __restrict__ dst,
    const int* __restrict__ slot, const int* __restrict__ rowstart,
    int* __restrict__ srcperm) {
    int e0 = (blockIdx.x * 256 + threadIdx.x) * 4;
    if (e0 >= N_EDGES) return;
    int4 s = *(const int4*)(src + e0);
    int4 d = *(const int4*)(dst + e0);
    int4 sl = *(const int4*)(slot + e0);
    srcperm[rowstart[d.x] + sl.x] = s.x << 7;   // 128 B row stride (fp16/bf16)
    srcperm[rowstart[d.y] + sl.y] = s.y << 7;
    srcperm[rowstart[d.z] + sl.z] = s.z << 7;
    srcperm[rowstart[d.w] + sl.w] = s.w << 7;
}

// ---- K5: fused per-node logits + online softmax + weighted f-aggregation ----
// One wave per dst node. Logit: 8 lanes/edge, fp16 k rows via v_dot2_f32_f16.
// Accumulate: 2 edges/step, 2 dims/lane packed bf16, cross-half shfl reduce.
__global__ __launch_bounds__(256) void node_agg_k(
    const int* __restrict__ rowstart, const int* __restrict__ srcperm,
    const float* __restrict__ q, const unsigned short* __restrict__ kh,
    const unsigned short* __restrict__ fb, float* __restrict__ out) {

    __shared__ float lg[4][AGG_CHUNK];
    __shared__ int   si[4][AGG_CHUNK];

    int wave = threadIdx.x >> 6;
    int lane = threadIdx.x & 63;
    int n    = blockIdx.x * 4 + wave;
    if (n >= N_NODES) return;

    int r0 = rowstart[n], r1 = rowstart[n + 1];
    int len = r1 - r0;

    // q row (fp32) -> fp16 pairs, per 8-lane group
    const int l8 = lane & 7;
    const float4* q4 = (const float4*)(q + (size_t)n * D + l8 * 8);
    float4 qa = q4[0], qb = q4[1];
    half2v qp0 = {(_Float16)qa.x, (_Float16)qa.y};
    half2v qp1 = {(_Float16)qa.z, (_Float16)qa.w};
    half2v qp2 = {(_Float16)qb.x, (_Float16)qb.y};
    half2v qp3 = {(_Float16)qb.z, (_Float16)qb.w};

    const char* kbase = (const char*)kh;
    const char* fbase = (const char*)fb;
    const int half_ = lane >> 5;          // 0/1: edge parity in accumulate
    const int ld    = lane & 31;          // dim-pair index (dims 2ld, 2ld+1)

    float acc0 = 0.0f, acc1 = 0.0f;
    float m = -INFINITY, l = 0.0f;

    for (int c0 = r0; c0 < r1; c0 += AGG_CHUNK) {
        int cnt = min(AGG_CHUNK, r1 - c0);

        // stage byte-offsets for the chunk (coalesced)
        for (int i = lane; i < cnt; i += 64) si[wave][i] = srcperm[c0 + i];
        __asm__ volatile("s_waitcnt lgkmcnt(0)" ::: "memory");

        // --- logit pass: 8 edges per wave-step ---
        for (int base = 0; base < cnt; base += 8) {
            int i = base + (lane >> 3);
            float dot = 0.0f;
            if (i < cnt) {
                int off = si[wave][i];
                uint4 u = *(const uint4*)(kbase + off + l8 * 16);
                dot = fdot2(u.x, qp0, dot);
                dot = fdot2(u.y, qp1, dot);
                dot = fdot2(u.z, qp2, dot);
                dot = fdot2(u.w, qp3, dot);
            }
            dot += __shfl_xor(dot, 1);
            dot += __shfl_xor(dot, 2);
            dot += __shfl_xor(dot, 4);
            if (l8 == 0 && i < cnt)
                lg[wave][i] = dot > 0.0f ? dot : NEG_SLOPE * dot;
        }
        __asm__ volatile("s_waitcnt lgkmcnt(0)" ::: "memory");

        // --- chunk max + online rescale ---
        float cm = -INFINITY;
        for (int i = lane; i < cnt; i += 64) cm = fmaxf(cm, lg[wave][i]);
        #pragma unroll
        for (int off = 32; off; off >>= 1) cm = fmaxf(cm, __shfl_xor(cm, off));
        float mnew  = fmaxf(m, cm);
        float scale = __expf(m - mnew);
        l    *= scale;
        acc0 *= scale;
        acc1 *= scale;

        // --- exp + partial sum (exp stored back to LDS) ---
        float es = 0.0f;
        for (int i = lane; i < cnt; i += 64) {
            float ez = __expf(lg[wave][i] - mnew);
            lg[wave][i] = ez;
            es += ez;
        }
        #pragma unroll
        for (int off = 32; off; off >>= 1) es += __shfl_xor(es, off);
        l += es;
        m  = mnew;
        __asm__ volatile("s_waitcnt lgkmcnt(0)" ::: "memory");

        // --- weighted accumulate: 2 edges/step, 2 dims/lane ---
        int i = 0;
        for (; i + 2 <= cnt; i += 2) {
            int ii = i + half_;
            float w  = lg[wave][ii];
            int  off = si[wave][ii];
            unsigned u = *(const unsigned*)(fbase + off + ld * 4);
            acc0 = fmaf(w, blo(u), acc0);
            acc1 = fmaf(w, bhi(u), acc1);
        }
        if (i < cnt) {                       // odd tail: upper half contributes 0
            float w  = half_ ? 0.0f : lg[wave][i];
            int  off = si[wave][i];
            unsigned u = *(const unsigned*)(fbase + off + ld * 4);
            acc0 = fmaf(w, blo(u), acc0);
            acc1 = fmaf(w, bhi(u), acc1);
        }
    }

    // cross-half reduce (edge parity halves hold same dims)
    acc0 += __shfl_xor(acc0, 32);
    acc1 += __shfl_xor(acc1, 32);
    float inv = (len > 0) ? 1.0f / l : 0.0f;
    if (lane < 32) {
        float2 o = make_float2(acc0 * inv, acc1 * inv);
        *((float2*)(out + (size_t)n * D) + ld) = o;
    }
}

extern "C" void kernel_launch(void* const* d_in, const int* in_sizes, int n_in,
                              void* d_out, int out_size, void* d_ws, size_t ws_size,
                              hipStream_t stream) {
    const float* feat = (const float*)d_in[0];
    const int*   src  = (const int*)d_in[1];
    const int*   dst  = (const int*)d_in[2];
    const float* Wq   = (const float*)d_in[3];
    const float* bq   = (const float*)d_in[4];
    const float* Wk   = (const float*)d_in[5];
    const float* bk   = (const float*)d_in[6];
    const float* Wf   = (const float*)d_in[7];
    const float* bf   = (const float*)d_in[8];
    float* out = (float*)d_out;

    // workspace: q(f32) | kh(fp16) | fb(bf16) | srcperm | slot | rowstart | counts | blocksum
    float*          q        = (float*)d_ws;
    unsigned short* kh       = (unsigned short*)(q + (size_t)N_NODES * D);
    unsigned short* fb       = kh + (size_t)N_NODES * D;
    int*            srcperm  = (int*)(fb + (size_t)N_NODES * D);
    int*            slot     = srcperm + N_EDGES;
    int*            rowstart = slot + N_EDGES;            // N_NODES + 1
    int*            counts   = rowstart + N_NODES + 1;
    int*            blocksum = counts + N_NODES;          // NB_SCAN (<=128)

    hipMemsetAsync(counts, 0, N_NODES * sizeof(int), stream);

    proj_k<<<PROJ_BLOCKS, 256, 0, stream>>>(
        feat, Wq, bq, Wk, bk, Wf, bf, q, kh, fb);

    hist_k<<<(N_EDGES / 4 + 255) / 256, 256, 0, stream>>>(dst, counts, slot);

    scan1_k<<<NB_SCAN, 256, 0, stream>>>(counts, rowstart, blocksum);
    scan23_k<<<(N_NODES + 255) / 256, 256, 0, stream>>>(rowstart, blocksum);

    scatter_k<<<(N_EDGES / 4 + 255) / 256, 256, 0, stream>>>(
        src, dst, slot, rowstart, srcperm);

    node_agg_k<<<(N_NODES + 3) / 4, 256, 0, stream>>>(rowstart, srcperm, q, kh, fb, out);
}

// Round 8
// 296.069 us; speedup vs baseline: 1.0415x; 1.0415x over previous
//
#include <hip/hip_runtime.h>
#include <math.h>

#define N_NODES   100000
#define N_EDGES   1600000
#define D         64
#define NEG_SLOPE 0.2f

#define SCAN_CHUNK 1024
#define NB_SCAN    ((N_NODES + SCAN_CHUNK - 1) / SCAN_CHUNK)   // 98

#define AGG_CHUNK 128   // edges per online-softmax chunk (LDS buffered)

typedef __attribute__((ext_vector_type(8))) _Float16 half8;
typedef __attribute__((ext_vector_type(2))) _Float16 half2v;
typedef __attribute__((ext_vector_type(4))) float floatx4;

// fp32 -> bf16 bits, round-to-nearest-even
__device__ __forceinline__ unsigned short bfbits(float x) {
    unsigned u = __float_as_uint(x);
    u += 0x7fffu + ((u >> 16) & 1u);
    return (unsigned short)(u >> 16);
}
__device__ __forceinline__ float blo(unsigned v) { return __uint_as_float(v << 16); }
__device__ __forceinline__ float bhi(unsigned v) { return __uint_as_float(v & 0xffff0000u); }
// fp32 -> fp16 bits (RTE)
__device__ __forceinline__ unsigned short h16(float x) {
    union { _Float16 h; unsigned short u; } c; c.h = (_Float16)x; return c.u;
}
__device__ __forceinline__ half2v u2h(unsigned v) {
    union { unsigned u; half2v h; } c; c.u = v; return c.h;
}
__device__ __forceinline__ float fdot2(unsigned a, half2v b, float c) {
#if __has_builtin(__builtin_amdgcn_fdot2)
    return __builtin_amdgcn_fdot2(u2h(a), b, c, false);
#else
    half2v ah = u2h(a);
    return c + (float)ah[0] * (float)b[0] + (float)ah[1] * (float)b[1];
#endif
}

// ---- K1: fp16-MFMA projection: q(fp32), k(fp16), f(bf16) = feat @ {Wq,Wk,Wf} + b
// Layouts (gfx950 16x16x32, dtype-independent C/D): A[m=lane&15][k=quad*8+j],
// B[n=lane&15][k=quad*8+j], D: col=lane&15, row=quad*4+reg. 100000 = 16*6250 (no tail).
#define WT_STRIDE 72            // fp16 elems; 144 B row stride (16B-aligned)
#define PROJ_BLOCKS 512
#define PROJ_WAVES  (PROJ_BLOCKS * 4)
__global__ __launch_bounds__(256, 2) void proj_k(
    const float* __restrict__ feat,
    const float* __restrict__ Wq, const float* __restrict__ bq,
    const float* __restrict__ Wk, const float* __restrict__ bk,
    const float* __restrict__ Wf, const float* __restrict__ bf,
    float* __restrict__ q, unsigned short* __restrict__ kh,
    unsigned short* __restrict__ fb) {

    __shared__ unsigned short wt[3 * 64 * WT_STRIDE];   // 27 KB, fp16 bits

    const int tid  = threadIdx.x;
    const int lane = tid & 63;
    const int wave = tid >> 6;
    const int m    = lane & 15;
    const int quad = lane >> 4;

    // stage W^T into LDS as fp16: wt[w][n][k]
    for (int idx = tid; idx < 64 * 64; idx += 256) {
        int i = idx >> 6, d = idx & 63;                  // i = k-dim, d = out-dim
        int o = d * WT_STRIDE + i;
        wt[0 * 64 * WT_STRIDE + o] = h16(Wq[idx]);
        wt[1 * 64 * WT_STRIDE + o] = h16(Wk[idx]);
        wt[2 * 64 * WT_STRIDE + o] = h16(Wf[idx]);
    }
    __syncthreads();

    // register-resident B fragments + bias
    half8 Bf[3][4][2];
    float bias[3][4];
    #pragma unroll
    for (int w = 0; w < 3; w++)
        #pragma unroll
        for (int nt = 0; nt < 4; nt++) {
            int n = nt * 16 + m;
            #pragma unroll
            for (int ks = 0; ks < 2; ks++)
                Bf[w][nt][ks] = *(const half8*)&wt[(w * 64 + n) * WT_STRIDE + ks * 32 + quad * 8];
        }
    #pragma unroll
    for (int nt = 0; nt < 4; nt++) {
        int n = nt * 16 + m;
        bias[0][nt] = bq[n]; bias[1][nt] = bk[n]; bias[2][nt] = bf[n];
    }

    const int NT  = N_NODES / 16;          // 6250 exact
    const int wid = blockIdx.x * 4 + wave;

    for (int t = wid; t < NT; t += PROJ_WAVES) {
        int t0  = t * 16;
        int row = t0 + m;

        const floatx4* fr = (const floatx4*)(feat + (size_t)row * D + quad * 8);
        floatx4 x0 = fr[0], x1 = fr[1];    // k-dims quad*8..+7      (kstep 0)
        floatx4 x2 = fr[8], x3 = fr[9];    // k-dims 32+quad*8..+7   (kstep 1)

        half8 a0, a1;
        a0[0] = (_Float16)x0.x; a0[1] = (_Float16)x0.y;
        a0[2] = (_Float16)x0.z; a0[3] = (_Float16)x0.w;
        a0[4] = (_Float16)x1.x; a0[5] = (_Float16)x1.y;
        a0[6] = (_Float16)x1.z; a0[7] = (_Float16)x1.w;
        a1[0] = (_Float16)x2.x; a1[1] = (_Float16)x2.y;
        a1[2] = (_Float16)x2.z; a1[3] = (_Float16)x2.w;
        a1[4] = (_Float16)x3.x; a1[5] = (_Float16)x3.y;
        a1[6] = (_Float16)x3.z; a1[7] = (_Float16)x3.w;

        floatx4 acc[3][4];
        #pragma unroll
        for (int w = 0; w < 3; w++)
            #pragma unroll
            for (int nt = 0; nt < 4; nt++) {
                floatx4 c = {bias[w][nt], bias[w][nt], bias[w][nt], bias[w][nt]};
                c = __builtin_amdgcn_mfma_f32_16x16x32_f16(a0, Bf[w][nt][0], c, 0, 0, 0);
                c = __builtin_amdgcn_mfma_f32_16x16x32_f16(a1, Bf[w][nt][1], c, 0, 0, 0);
                acc[w][nt] = c;
            }

        #pragma unroll
        for (int nt = 0; nt < 4; nt++) {
            int dim = nt * 16 + m;
            #pragma unroll
            for (int r = 0; r < 4; r++) {
                int node = t0 + quad * 4 + r;
                size_t o = (size_t)node * D + dim;
                q[o]  = acc[0][nt][r];
                kh[o] = h16(acc[1][nt][r]);
                fb[o] = bfbits(acc[2][nt][r]);
            }
        }
    }
}

// ---- K2: histogram of dst, 4 edges/thread; slot written as int4 ----
__global__ __launch_bounds__(256) void hist_k(const int* __restrict__ dst,
                                              int* __restrict__ counts,
                                              int* __restrict__ slot) {
    int e0 = (blockIdx.x * 256 + threadIdx.x) * 4;
    if (e0 >= N_EDGES) return;               // N_EDGES % 4 == 0
    int4 d = *(const int4*)(dst + e0);
    int4 s;
    s.x = atomicAdd(&counts[d.x], 1);
    s.y = atomicAdd(&counts[d.y], 1);
    s.z = atomicAdd(&counts[d.z], 1);
    s.w = atomicAdd(&counts[d.w], 1);
    *(int4*)(slot + e0) = s;
}

// ---- K3a: per-block exclusive scan (1024 elems/block), raw blocksum out ----
__global__ __launch_bounds__(256) void scan1_k(const int* __restrict__ counts,
                                               int* __restrict__ rowstart,
                                               int* __restrict__ blocksum) {
    __shared__ int lds[256];
    int base = blockIdx.x * SCAN_CHUNK + threadIdx.x * 4;
    int c[4]; int s = 0;
    #pragma unroll
    for (int u = 0; u < 4; u++) {
        int idx = base + u;
        c[u] = (idx < N_NODES) ? counts[idx] : 0;
        s += c[u];
    }
    lds[threadIdx.x] = s;
    __syncthreads();
    for (int off = 1; off < 256; off <<= 1) {
        int v = (threadIdx.x >= off) ? lds[threadIdx.x - off] : 0;
        __syncthreads();
        lds[threadIdx.x] += v;
        __syncthreads();
    }
    int run = (threadIdx.x == 0) ? 0 : lds[threadIdx.x - 1];
    if (threadIdx.x == 255) blocksum[blockIdx.x] = lds[255];
    #pragma unroll
    for (int u = 0; u < 4; u++) {
        int idx = base + u;
        if (idx < N_NODES) rowstart[idx] = run;
        run += c[u];
    }
}

// ---- K3b: add block offsets (each block scans the raw blocksums itself) ----
__global__ __launch_bounds__(256) void scan23_k(int* __restrict__ rowstart,
                                                const int* __restrict__ blocksum) {
    __shared__ int lds[128];
    int t = threadIdx.x;
    if (t < 128) lds[t] = (t < NB_SCAN) ? blocksum[t] : 0;
    __syncthreads();
    for (int off = 1; off < 128; off <<= 1) {
        int v = 0;
        if (t < 128 && t >= off) v = lds[t - off];
        __syncthreads();
        if (t < 128) lds[t] += v;
        __syncthreads();
    }
    int i = blockIdx.x * 256 + t;
    if (i < N_NODES) {
        int ci = i / SCAN_CHUNK;
        rowstart[i] += (ci ? lds[ci - 1] : 0);
    }
    if (i == 0) rowstart[N_NODES] = N_EDGES;
}

// ---- K4: scatter (src<<7) byte-offsets into CSR slots, 4 edges/thread ----
__global__ __launch_bounds__(256) void scatter_k(
    const int* __restrict__ src, const int* __restrict__ dst,
    const int* __restrict__ slot, const int* __restrict__ rowstart,
    int* __restrict__ srcperm) {
    int e0 = (blockIdx.x * 256 + threadIdx.x) * 4;
    if (e0 >= N_EDGES) return;
    int4 s = *(const int4*)(src + e0);
    int4 d = *(const int4*)(dst + e0);
    int4 sl = *(const int4*)(slot + e0);
    srcperm[rowstart[d.x] + sl.x] = s.x << 7;   // 128 B row stride (fp16/bf16)
    srcperm[rowstart[d.y] + sl.y] = s.y << 7;
    srcperm[rowstart[d.z] + sl.z] = s.z << 7;
    srcperm[rowstart[d.w] + sl.w] = s.w << 7;
}

// ---- K5: fused per-node logits + online softmax + weighted f-aggregation ----
// R6 pipeline shape (direct global srcperm loads in logit, 2 barriers/chunk)
// + fdot2 logit dot + packed 2-dims/lane accumulate, 4x unrolled (8 edges/iter).
__global__ __launch_bounds__(256) void node_agg_k(
    const int* __restrict__ rowstart, const int* __restrict__ srcperm,
    const float* __restrict__ q, const unsigned short* __restrict__ kh,
    const unsigned short* __restrict__ fb, float* __restrict__ out) {

    __shared__ float lg[4][AGG_CHUNK];
    __shared__ int   si[4][AGG_CHUNK];

    int wave = threadIdx.x >> 6;
    int lane = threadIdx.x & 63;
    int n    = blockIdx.x * 4 + wave;
    if (n >= N_NODES) return;

    int r0 = rowstart[n], r1 = rowstart[n + 1];
    int len = r1 - r0;

    // q row (fp32) -> fp16 pairs, per 8-lane group
    const int l8 = lane & 7;
    const float4* q4 = (const float4*)(q + (size_t)n * D + l8 * 8);
    float4 qa = q4[0], qb = q4[1];
    half2v qp0 = {(_Float16)qa.x, (_Float16)qa.y};
    half2v qp1 = {(_Float16)qa.z, (_Float16)qa.w};
    half2v qp2 = {(_Float16)qb.x, (_Float16)qb.y};
    half2v qp3 = {(_Float16)qb.z, (_Float16)qb.w};

    const char* kbase = (const char*)kh;
    const char* fbase = (const char*)fb;
    const int half_ = lane >> 5;          // 0/1: edge parity in accumulate
    const int ld    = lane & 31;          // dim-pair index (dims 2ld, 2ld+1)

    float acc0 = 0.0f, acc1 = 0.0f;
    float m = -INFINITY, l = 0.0f;

    for (int c0 = r0; c0 < r1; c0 += AGG_CHUNK) {
        int cnt = min(AGG_CHUNK, r1 - c0);

        // --- logit pass: 8 edges per wave-step, direct global srcperm load ---
        for (int base = 0; base < cnt; base += 8) {
            int i = base + (lane >> 3);
            float dot = 0.0f;
            int off = 0;
            if (i < cnt) {
                off = srcperm[c0 + i];
                uint4 u = *(const uint4*)(kbase + off + l8 * 16);
                dot = fdot2(u.x, qp0, dot);
                dot = fdot2(u.y, qp1, dot);
                dot = fdot2(u.z, qp2, dot);
                dot = fdot2(u.w, qp3, dot);
            }
            dot += __shfl_xor(dot, 1);
            dot += __shfl_xor(dot, 2);
            dot += __shfl_xor(dot, 4);
            if (l8 == 0 && i < cnt) {
                lg[wave][i] = dot > 0.0f ? dot : NEG_SLOPE * dot;
                si[wave][i] = off;
            }
        }
        __asm__ volatile("s_waitcnt lgkmcnt(0)" ::: "memory");

        // --- chunk max + online rescale ---
        float cm = -INFINITY;
        for (int i = lane; i < cnt; i += 64) cm = fmaxf(cm, lg[wave][i]);
        #pragma unroll
        for (int off = 32; off; off >>= 1) cm = fmaxf(cm, __shfl_xor(cm, off));
        float mnew  = fmaxf(m, cm);
        float scale = __expf(m - mnew);
        l    *= scale;
        acc0 *= scale;
        acc1 *= scale;

        // --- exp + partial sum (exp stored back to LDS) ---
        float es = 0.0f;
        for (int i = lane; i < cnt; i += 64) {
            float ez = __expf(lg[wave][i] - mnew);
            lg[wave][i] = ez;
            es += ez;
        }
        #pragma unroll
        for (int off = 32; off; off >>= 1) es += __shfl_xor(es, off);
        l += es;
        m  = mnew;
        __asm__ volatile("s_waitcnt lgkmcnt(0)" ::: "memory");

        // --- weighted accumulate: 2 edges/step, 2 dims/lane, 4x unrolled ---
        int i = 0;
        for (; i + 8 <= cnt; i += 8) {
            int   i0 = i + half_, i1 = i + 2 + half_, i2 = i + 4 + half_, i3 = i + 6 + half_;
            float w0 = lg[wave][i0], w1 = lg[wave][i1];
            float w2 = lg[wave][i2], w3 = lg[wave][i3];
            int   o0 = si[wave][i0], o1 = si[wave][i1];
            int   o2 = si[wave][i2], o3 = si[wave][i3];
            unsigned u0 = *(const unsigned*)(fbase + o0 + ld * 4);
            unsigned u1 = *(const unsigned*)(fbase + o1 + ld * 4);
            unsigned u2 = *(const unsigned*)(fbase + o2 + ld * 4);
            unsigned u3 = *(const unsigned*)(fbase + o3 + ld * 4);
            acc0 = fmaf(w0, blo(u0), acc0); acc1 = fmaf(w0, bhi(u0), acc1);
            acc0 = fmaf(w1, blo(u1), acc0); acc1 = fmaf(w1, bhi(u1), acc1);
            acc0 = fmaf(w2, blo(u2), acc0); acc1 = fmaf(w2, bhi(u2), acc1);
            acc0 = fmaf(w3, blo(u3), acc0); acc1 = fmaf(w3, bhi(u3), acc1);
        }
        for (; i + 2 <= cnt; i += 2) {
            int ii = i + half_;
            float w  = lg[wave][ii];
            int  off = si[wave][ii];
            unsigned u = *(const unsigned*)(fbase + off + ld * 4);
            acc0 = fmaf(w, blo(u), acc0);
            acc1 = fmaf(w, bhi(u), acc1);
        }
        if (i < cnt) {                       // odd tail: upper half contributes 0
            float w  = half_ ? 0.0f : lg[wave][i];
            int  off = si[wave][i];
            unsigned u = *(const unsigned*)(fbase + off + ld * 4);
            acc0 = fmaf(w, blo(u), acc0);
            acc1 = fmaf(w, bhi(u), acc1);
        }
    }

    // cross-half reduce (edge parity halves hold same dims)
    acc0 += __shfl_xor(acc0, 32);
    acc1 += __shfl_xor(acc1, 32);
    float inv = (len > 0) ? 1.0f / l : 0.0f;
    if (lane < 32) {
        float2 o = make_float2(acc0 * inv, acc1 * inv);
        *((float2*)(out + (size_t)n * D) + ld) = o;
    }
}

extern "C" void kernel_launch(void* const* d_in, const int* in_sizes, int n_in,
                              void* d_out, int out_size, void* d_ws, size_t ws_size,
                              hipStream_t stream) {
    const float* feat = (const float*)d_in[0];
    const int*   src  = (const int*)d_in[1];
    const int*   dst  = (const int*)d_in[2];
    const float* Wq   = (const float*)d_in[3];
    const float* bq   = (const float*)d_in[4];
    const float* Wk   = (const float*)d_in[5];
    const float* bk   = (const float*)d_in[6];
    const float* Wf   = (const float*)d_in[7];
    const float* bf   = (const float*)d_in[8];
    float* out = (float*)d_out;

    // workspace: q(f32) | kh(fp16) | fb(bf16) | srcperm | slot | rowstart | counts | blocksum
    float*          q        = (float*)d_ws;
    unsigned short* kh       = (unsigned short*)(q + (size_t)N_NODES * D);
    unsigned short* fb       = kh + (size_t)N_NODES * D;
    int*            srcperm  = (int*)(fb + (size_t)N_NODES * D);
    int*            slot     = srcperm + N_EDGES;
    int*            rowstart = slot + N_EDGES;            // N_NODES + 1
    int*            counts   = rowstart + N_NODES + 1;
    int*            blocksum = counts + N_NODES;          // NB_SCAN (<=128)

    hipMemsetAsync(counts, 0, N_NODES * sizeof(int), stream);

    proj_k<<<PROJ_BLOCKS, 256, 0, stream>>>(
        feat, Wq, bq, Wk, bk, Wf, bf, q, kh, fb);

    hist_k<<<(N_EDGES / 4 + 255) / 256, 256, 0, stream>>>(dst, counts, slot);

    scan1_k<<<NB_SCAN, 256, 0, stream>>>(counts, rowstart, blocksum);
    scan23_k<<<(N_NODES + 255) / 256, 256, 0, stream>>>(rowstart, blocksum);

    scatter_k<<<(N_EDGES / 4 + 255) / 256, 256, 0, stream>>>(
        src, dst, slot, rowstart, srcperm);

    node_agg_k<<<(N_NODES + 3) / 4, 256, 0, stream>>>(rowstart, srcperm, q, kh, fb, out);
}